// Round 2
// baseline (2305.856 us; speedup 1.0000x reference)
//
#include <hip/hip_runtime.h>

#define HDIM 64
#define NSTEPS 4

// Packed weight layout in d_ws (float offsets):
//   [0,    256): L1 pack: per k, float4 (W1[k][0], W1[k][1], W1[k][2], b1[k])
//   [256, 4352): W2T[k][j] = W2[j][k+1]                  (64x64)
//   [4352,8448): QT[k][j]  = P[k][j] * W2[j][k+1]        (64x64)
//                where P[k][j] = W1[k][1]*W3[0][j+1] + W1[k][2]*W3[1][j+1]
//   [8448,8576): C2 per j: float2 (W2[j][0], b2[j])
//   [8576,8704): L3 per j: float2 (W3[0][j+1], W3[1][j+1])
//   [8704,8708): C3: (W3[0][0], W3[1][0], b3[0], b3[1])

__global__ void ffjord_prep(const float* __restrict__ W1, const float* __restrict__ b1,
                            const float* __restrict__ W2, const float* __restrict__ b2,
                            const float* __restrict__ W3, const float* __restrict__ b3,
                            float* __restrict__ ws) {
  int tid = threadIdx.x;  // single block, 256 threads
  if (tid < HDIM) {
    ws[tid * 4 + 0] = W1[tid * 3 + 0];
    ws[tid * 4 + 1] = W1[tid * 3 + 1];
    ws[tid * 4 + 2] = W1[tid * 3 + 2];
    ws[tid * 4 + 3] = b1[tid];
    ws[8448 + tid * 2 + 0] = W2[tid * 65 + 0];
    ws[8448 + tid * 2 + 1] = b2[tid];
    ws[8576 + tid * 2 + 0] = W3[0 * 65 + tid + 1];
    ws[8576 + tid * 2 + 1] = W3[1 * 65 + tid + 1];
  }
  if (tid == 0) {
    ws[8704] = W3[0];
    ws[8705] = W3[65];
    ws[8706] = b3[0];
    ws[8707] = b3[1];
  }
  for (int e = tid; e < HDIM * HDIM; e += 256) {
    int k = e >> 6, j = e & 63;
    float w2 = W2[j * 65 + k + 1];
    float p = W1[k * 3 + 1] * W3[j + 1] + W1[k * 3 + 2] * W3[65 + j + 1];
    ws[256 + e] = w2;       // W2T[k][j]
    ws[4352 + e] = p * w2;  // QT[k][j]
  }
}

__device__ __forceinline__ float sigmoid_fast(float a) {
  float e = __expf(-fabsf(a));
  float r = __builtin_amdgcn_rcpf(1.0f + e);
  return (a >= 0.f ? 1.0f : e) * r;
}

__global__ __launch_bounds__(256, 4) void ffjord_main(
    const float* __restrict__ z_in, const float* __restrict__ dlp_in,
    const float* __restrict__ ws, float* __restrict__ out, int B) {
  int i = blockIdx.x * 256 + threadIdx.x;
  if (i >= B) return;

  const float4* L1  = (const float4*)(ws);
  const float*  W2T = ws + 256;
  const float*  QT  = ws + 4352;
  const float2* C2  = (const float2*)(ws + 8448);
  const float2* L3  = (const float2*)(ws + 8576);
  const float c30 = ws[8704], c31 = ws[8705], cb0 = ws[8706], cb1 = ws[8707];

  float z0 = z_in[2 * i], z1 = z_in[2 * i + 1];
  float l = dlp_in[i];
  const float dt = 1.0f / NSTEPS;

  #pragma unroll 1
  for (int step = 0; step < NSTEPS; ++step) {
    float t0 = step * dt;
    float az0 = 0.f, az1 = 0.f, al = 0.f;
    float zt0 = z0, zt1 = z1, ts = t0;

    #pragma unroll 1
    for (int s = 0; s < 4; ++s) {
      // ---- Pass 1: h2[j] = W2[:,0]*t + b2 + sum_k W2T[k][j]*softplus(a_k) ----
      float h2[HDIM];
      #pragma unroll
      for (int j = 0; j < HDIM; ++j) {
        float2 c2 = C2[j];
        h2[j] = fmaf(c2.x, ts, c2.y);
      }

      #pragma unroll 2
      for (int k = 0; k < HDIM; ++k) {
        float4 w1 = L1[k];
        float a = fmaf(w1.x, ts, fmaf(w1.y, zt0, fmaf(w1.z, zt1, w1.w)));
        float e = __expf(-fabsf(a));
        float sp = fmaxf(a, 0.f) + __logf(1.0f + e);  // softplus(a)
        const float* w2row = W2T + k * 64;
        #pragma unroll
        for (int j = 0; j < HDIM; ++j) {
          h2[j] = fmaf(w2row[j], sp, h2[j]);
        }
      }

      // ---- Mid: epilogue z_dot, and h2[j] <- sigmoid(h2[j]) in place ----
      float zd0 = fmaf(c30, ts, cb0);
      float zd1 = fmaf(c31, ts, cb1);
      #pragma unroll
      for (int j = 0; j < HDIM; ++j) {
        float a = h2[j];
        float e = __expf(-fabsf(a));
        float r = __builtin_amdgcn_rcpf(1.0f + e);
        float sg = (a >= 0.f ? 1.0f : e) * r;
        float sp = fmaxf(a, 0.f) + __logf(1.0f + e);
        float2 l3 = L3[j];
        zd0 = fmaf(l3.x, sp, zd0);
        zd1 = fmaf(l3.y, sp, zd1);
        h2[j] = sg;
      }

      // ---- Pass 2: dv = sum_k sigmoid(a_k) * (sum_j QT[k][j]*sg2[j]) ----
      float dv = 0.f;
      #pragma unroll 2
      for (int k = 0; k < HDIM; ++k) {
        float4 w1 = L1[k];
        float a = fmaf(w1.x, ts, fmaf(w1.y, zt0, fmaf(w1.z, zt1, w1.w)));
        float sg1 = sigmoid_fast(a);
        const float* qrow = QT + k * 64;
        float q0 = 0.f, q1 = 0.f, q2 = 0.f, q3 = 0.f;
        #pragma unroll
        for (int j = 0; j < HDIM; j += 4) {
          q0 = fmaf(qrow[j + 0], h2[j + 0], q0);
          q1 = fmaf(qrow[j + 1], h2[j + 1], q1);
          q2 = fmaf(qrow[j + 2], h2[j + 2], q2);
          q3 = fmaf(qrow[j + 3], h2[j + 3], q3);
        }
        dv = fmaf(sg1, (q0 + q1) + (q2 + q3), dv);
      }

      // ---- RK4 combine ----
      float w = (s == 1 || s == 2) ? 2.0f : 1.0f;
      az0 = fmaf(w, zd0, az0);
      az1 = fmaf(w, zd1, az1);
      al = fmaf(w, dv, al);
      if (s < 3) {
        float c = (s == 2) ? dt : 0.5f * dt;
        zt0 = fmaf(c, zd0, z0);
        zt1 = fmaf(c, zd1, z1);
        ts = t0 + c;
      }
    }
    z0 = fmaf(dt / 6.0f, az0, z0);
    z1 = fmaf(dt / 6.0f, az1, z1);
    l = fmaf(-dt / 6.0f, al, l);  // k_l = -div
  }

  out[2 * i] = z0;
  out[2 * i + 1] = z1;
  out[2 * B + i] = l;
}

extern "C" void kernel_launch(void* const* d_in, const int* in_sizes, int n_in,
                              void* d_out, int out_size, void* d_ws, size_t ws_size,
                              hipStream_t stream) {
  const float* z   = (const float*)d_in[0];
  const float* dlp = (const float*)d_in[1];
  const float* W1  = (const float*)d_in[2];
  const float* b1  = (const float*)d_in[3];
  const float* W2  = (const float*)d_in[4];
  const float* b2  = (const float*)d_in[5];
  const float* W3  = (const float*)d_in[6];
  const float* b3  = (const float*)d_in[7];
  float* out = (float*)d_out;
  float* ws = (float*)d_ws;

  int B = in_sizes[0] / 2;

  ffjord_prep<<<1, 256, 0, stream>>>(W1, b1, W2, b2, W3, b3, ws);
  int blocks = (B + 255) / 256;
  ffjord_main<<<blocks, 256, 0, stream>>>(z, dlp, ws, out, B);
}

// Round 4
// 1485.376 us; speedup vs baseline: 1.5524x; 1.5524x over previous
//
#include <hip/hip_runtime.h>

#define HDIM 64
#define NSTEPS 4

typedef __fp16 half2_t __attribute__((ext_vector_type(2)));

// Packed weight layout in d_ws (float offsets):
//   [0,    256): L1 pack: per k, float4 (W1[k][0], W1[k][1], W1[k][2], b1[k])
//   [256, 4352): W2T[k][j] = W2[j][k+1]                  (64x64)
//   [4352,8448): QT[k][j]  = P[k][j] * W2[j][k+1]        (64x64)
//                where P[k][j] = W1[k][1]*W3[0][j+1] + W1[k][2]*W3[1][j+1]
//   [8448,8576): C2 per j: float2 (W2[j][0], b2[j])
//   [8576,8704): L3 per j: float2 (W3[0][j+1], W3[1][j+1])
//   [8704,8708): C3: (W3[0][0], W3[1][0], b3[0], b3[1])

__global__ void ffjord_prep(const float* __restrict__ W1, const float* __restrict__ b1,
                            const float* __restrict__ W2, const float* __restrict__ b2,
                            const float* __restrict__ W3, const float* __restrict__ b3,
                            float* __restrict__ ws) {
  int tid = threadIdx.x;  // single block, 256 threads
  if (tid < HDIM) {
    ws[tid * 4 + 0] = W1[tid * 3 + 0];
    ws[tid * 4 + 1] = W1[tid * 3 + 1];
    ws[tid * 4 + 2] = W1[tid * 3 + 2];
    ws[tid * 4 + 3] = b1[tid];
    ws[8448 + tid * 2 + 0] = W2[tid * 65 + 0];
    ws[8448 + tid * 2 + 1] = b2[tid];
    ws[8576 + tid * 2 + 0] = W3[0 * 65 + tid + 1];
    ws[8576 + tid * 2 + 1] = W3[1 * 65 + tid + 1];
  }
  if (tid == 0) {
    ws[8704] = W3[0];
    ws[8705] = W3[65];
    ws[8706] = b3[0];
    ws[8707] = b3[1];
  }
  for (int e = tid; e < HDIM * HDIM; e += 256) {
    int k = e >> 6, j = e & 63;
    float w2 = W2[j * 65 + k + 1];
    float p = W1[k * 3 + 1] * W3[j + 1] + W1[k * 3 + 2] * W3[65 + j + 1];
    ws[256 + e] = w2;       // W2T[k][j]
    ws[4352 + e] = p * w2;  // QT[k][j]
  }
}

__global__ __launch_bounds__(256, 2) void ffjord_main(
    const float* __restrict__ z_in, const float* __restrict__ dlp_in,
    const float* __restrict__ ws, float* __restrict__ out, int B) {
  // Per-thread private activation stash: act[k][tid] = half2(softplus, sigmoid).
  // Lane-consecutive addressing -> 2-way bank aliasing (free). No barriers:
  // each thread only touches its own column.
  __shared__ unsigned int act[HDIM][256];

  int tid = threadIdx.x;
  int i = blockIdx.x * 256 + tid;
  if (i >= B) return;

  const float4* L1  = (const float4*)(ws);
  const float2* C2  = (const float2*)(ws + 8448);
  const float2* L3  = (const float2*)(ws + 8576);
  const float c30 = ws[8704], c31 = ws[8705], cb0 = ws[8706], cb1 = ws[8707];

  float z0 = z_in[2 * i], z1 = z_in[2 * i + 1];
  float l = dlp_in[i];
  const float dt = 1.0f / NSTEPS;

  #pragma unroll 1
  for (int step = 0; step < NSTEPS; ++step) {
    float t0 = step * dt;
    float az0 = 0.f, az1 = 0.f, al = 0.f;
    float zt0 = z0, zt1 = z1, ts = t0;

    #pragma unroll 1
    for (int s = 0; s < 4; ++s) {
      // ---- Pass A: layer-1 activations -> LDS (fp16 pair) ----
      #pragma unroll 4
      for (int k = 0; k < HDIM; ++k) {
        float4 w1 = L1[k];
        float a = fmaf(w1.x, ts, fmaf(w1.y, zt0, fmaf(w1.z, zt1, w1.w)));
        float e = __expf(-fabsf(a));
        float r = __builtin_amdgcn_rcpf(1.0f + e);
        float sg = (a >= 0.f ? 1.0f : e) * r;            // sigmoid(a)
        float sp = fmaxf(a, 0.f) + __logf(1.0f + e);     // softplus(a)
        half2_t h = __builtin_amdgcn_cvt_pkrtz(sp, sg);
        act[k][tid] = __builtin_bit_cast(unsigned int, h);
      }

      // ---- Pass B: j-blocked matvecs h2 = W2T^T sp, cq = QT^T sg ----
      float zd0 = fmaf(c30, ts, cb0);
      float zd1 = fmaf(c31, ts, cb1);
      float dv = 0.f;

      #pragma unroll 1
      for (int jb = 0; jb < 2; ++jb) {
        const float* w2b = ws + 256 + jb * 32;
        const float* qb  = ws + 4352 + jb * 32;

        float accH[32], accQ[32];
        #pragma unroll
        for (int j = 0; j < 32; ++j) {
          float2 c2 = C2[jb * 32 + j];
          accH[j] = fmaf(c2.x, ts, c2.y);
          accQ[j] = 0.f;
        }

        #pragma unroll 2
        for (int k = 0; k < HDIM; ++k) {
          half2_t h = __builtin_bit_cast(half2_t, act[k][tid]);
          float sp = (float)h[0];
          float sg = (float)h[1];
          const float* w2row = w2b + k * 64;
          const float* qrow  = qb + k * 64;
          #pragma unroll
          for (int j = 0; j < 32; ++j) {
            accH[j] = fmaf(w2row[j], sp, accH[j]);
            accQ[j] = fmaf(qrow[j], sg, accQ[j]);
          }
        }

        // Block epilogue: activation of h2, fold into zd / dv.
        #pragma unroll
        for (int j = 0; j < 32; ++j) {
          float a = accH[j];
          float e = __expf(-fabsf(a));
          float r = __builtin_amdgcn_rcpf(1.0f + e);
          float sg2 = (a >= 0.f ? 1.0f : e) * r;
          float sp2 = fmaxf(a, 0.f) + __logf(1.0f + e);
          float2 l3 = L3[jb * 32 + j];
          zd0 = fmaf(l3.x, sp2, zd0);
          zd1 = fmaf(l3.y, sp2, zd1);
          dv = fmaf(sg2, accQ[j], dv);
        }
      }

      // ---- RK4 combine ----
      float w = (s == 1 || s == 2) ? 2.0f : 1.0f;
      az0 = fmaf(w, zd0, az0);
      az1 = fmaf(w, zd1, az1);
      al = fmaf(w, dv, al);
      if (s < 3) {
        float c = (s == 2) ? dt : 0.5f * dt;
        zt0 = fmaf(c, zd0, z0);
        zt1 = fmaf(c, zd1, z1);
        ts = t0 + c;
      }
    }
    z0 = fmaf(dt / 6.0f, az0, z0);
    z1 = fmaf(dt / 6.0f, az1, z1);
    l = fmaf(-dt / 6.0f, al, l);  // k_l = -div
  }

  out[2 * i] = z0;
  out[2 * i + 1] = z1;
  out[2 * B + i] = l;
}

extern "C" void kernel_launch(void* const* d_in, const int* in_sizes, int n_in,
                              void* d_out, int out_size, void* d_ws, size_t ws_size,
                              hipStream_t stream) {
  const float* z   = (const float*)d_in[0];
  const float* dlp = (const float*)d_in[1];
  const float* W1  = (const float*)d_in[2];
  const float* b1  = (const float*)d_in[3];
  const float* W2  = (const float*)d_in[4];
  const float* b2  = (const float*)d_in[5];
  const float* W3  = (const float*)d_in[6];
  const float* b3  = (const float*)d_in[7];
  float* out = (float*)d_out;
  float* ws = (float*)d_ws;

  int B = in_sizes[0] / 2;

  ffjord_prep<<<1, 256, 0, stream>>>(W1, b1, W2, b2, W3, b3, ws);
  int blocks = (B + 255) / 256;
  ffjord_main<<<blocks, 256, 0, stream>>>(z, dlp, ws, out, B);
}